// Round 1
// 1449.455 us; speedup vs baseline: 1.6212x; 1.6212x over previous
//
#include <hip/hip_runtime.h>

#define A_CNT   5
#define NB      1024
#define DIM     512
#define NMEM    16384
#define TOPK    50
#define NSTEPS  5
#define H1N     256
#define H2N     128

#define TM      128
#define TN      128
#define MSEL    100     // screen candidates per row (slack over TOPK=50)
#define RCAP    512     // candidate buffer cap
#define KSTR    40      // LDS row stride in bf16 elems: 80 B = 20 banks -> <=2-way (free)

struct TileDesc { int a; int s0; int nvalid; int pad; };

typedef __bf16 bf16x8 __attribute__((ext_vector_type(8)));
typedef short  s16x8  __attribute__((ext_vector_type(8)));
typedef float  f32x4  __attribute__((ext_vector_type(4)));

// SFINAE hedge: gfx950 builtin takes v8bf16 (LLVM PR#116312) on most toolchains,
// v8i16 on others. Whichever signature exists compiles; the other overload is
// never instantiated.
template <typename T>
__device__ __forceinline__ auto mfma_try(T a, T b, f32x4 c, int)
    -> decltype(__builtin_amdgcn_mfma_f32_16x16x32_bf16(a, b, c, 0, 0, 0)) {
    return __builtin_amdgcn_mfma_f32_16x16x32_bf16(a, b, c, 0, 0, 0);
}
template <typename T>
__device__ __forceinline__ f32x4 mfma_try(T a, T b, f32x4 c, long) {
    return __builtin_amdgcn_mfma_f32_16x16x32_bf16(
        __builtin_bit_cast(s16x8, a), __builtin_bit_cast(s16x8, b), c, 0, 0, 0);
}
__device__ __forceinline__ f32x4 mfma_bf16(uint4 a, uint4 b, f32x4 c) {
    return mfma_try(__builtin_bit_cast(bf16x8, a), __builtin_bit_cast(bf16x8, b), c, 0);
}

union BF8 { bf16x8 v; uint4 u; };

__device__ __forceinline__ unsigned fmap16(unsigned u) {
    return (u & 0x8000u) ? ((~u) & 0xFFFFu) : (u | 0x8000u);
}

// ---------------------------------------------------------------------------
// ROUND-1 VERBATIM (selection-critical arithmetic — do not touch).
__global__ __launch_bounds__(256) void k_inv_norm(const float* __restrict__ keys,
                                                  float* __restrict__ inv) {
    int row  = blockIdx.x * 4 + (threadIdx.x >> 6);
    int lane = threadIdx.x & 63;
    const float* p = keys + (size_t)row * DIM;
    float ss = 0.f;
    for (int i = lane; i < DIM; i += 64) { float v = p[i]; ss += v * v; }
    for (int o = 32; o; o >>= 1) ss += __shfl_down(ss, o);
    ss = __shfl(ss, 0);
    if (lane == 0) inv[row] = 1.0f / (sqrtf(ss) + 1e-8f);
}

// ROUND-1 VERBATIM.
__global__ __launch_bounds__(256) void k_qnorm(const float* __restrict__ x,
                                               float* __restrict__ qn) {
    int row = blockIdx.x, tid = threadIdx.x;
    const float* p = x + (size_t)row * DIM;
    float ss = 0.f;
    for (int i = tid; i < DIM; i += 256) { float v = p[i]; ss += v * v; }
    for (int o = 32; o; o >>= 1) ss += __shfl_down(ss, o);
    __shared__ float w4[4];
    if ((tid & 63) == 0) w4[tid >> 6] = ss;
    __syncthreads();
    float tot = w4[0] + w4[1] + w4[2] + w4[3];
    float s = 1.0f / (sqrtf(tot) + 1e-8f);
    float* q = qn + (size_t)row * DIM;
    for (int i = tid; i < DIM; i += 256) q[i] = p[i] * s;
}

// ROUND-1 VERBATIM.
__global__ void k_group(const int* __restrict__ actions, int t,
                        int* __restrict__ sorted_b, int* __restrict__ sorted_a,
                        TileDesc* __restrict__ descs, int cb, int maxd, int nch) {
    int lane = threadIdx.x;  // blockDim = 64
    for (int i = lane; i < nch * maxd; i += 64) descs[i].a = -1;
    __shared__ int gs[A_CNT + 1];
    int out_pos = 0;
    for (int a = 0; a < A_CNT; a++) {
        if (lane == 0) gs[a] = out_pos;
        for (int c = 0; c < NB; c += 64) {
            int b = c + lane;
            int act = actions[b * NSTEPS + t];
            unsigned long long m = __ballot(act == a);
            int rank = __popcll(m & ((1ULL << lane) - 1ULL));
            if (act == a) { sorted_b[out_pos + rank] = b; sorted_a[out_pos + rank] = a; }
            out_pos += __popcll(m);
        }
    }
    if (lane == 0) {
        gs[A_CNT] = NB;
        int ndc[4] = {0, 0, 0, 0};
        for (int a = 0; a < A_CNT; a++) {
            int s = gs[a], e = gs[a + 1];
            while (s < e) {
                int c = s / cb;
                int lim = min(e, (c + 1) * cb);
                int len = min(TM, lim - s);
                TileDesc d; d.a = a; d.s0 = s; d.nvalid = len; d.pad = 0;
                descs[c * maxd + ndc[c]++] = d;
                s += len;
            }
        }
    }
}

// ---------------------------------------------------------------------------
// NEW k_screen: bf16 MFMA approximate-sims GEMM. Replaces the exact fp32
// k_gemm; exactness is restored per-candidate in k_topk (bit-identical fmaf
// chain). Computes D = K-tile * Q-tile^T so each lane holds 4 consecutive n
// per reg -> packed ushort4 stores. Both MFMA operands use the same
// (lane,j)->k map, so any HW k-permutation cancels (sum invariant).
__global__ __launch_bounds__(256) void k_screen(
    const float* __restrict__ qn, const float* __restrict__ keys,
    const float* __restrict__ inv_kn, const int* __restrict__ sorted_b,
    const TileDesc* __restrict__ descs, int chunk_row0,
    unsigned short* __restrict__ simsb) {
    TileDesc d = descs[blockIdx.y];
    if (d.a < 0) return;
    int tid = threadIdx.x;
    int n0 = blockIdx.x * TN;
    __shared__ __align__(16) unsigned short Qs[TM][KSTR];
    __shared__ __align__(16) unsigned short Ks[TN][KSTR];
    __shared__ int rows[TM];
    if (tid < TM) rows[tid] = sorted_b[d.s0 + min(tid, d.nvalid - 1)];
    __syncthreads();

    int w = tid >> 6, lane = tid & 63;
    int g = lane >> 4, r15 = lane & 15;
    int wq = w >> 1, wn = w & 1;   // wave covers q-rows wq*64.., n-cols wn*64..

    f32x4 acc[4][4];
#pragma unroll
    for (int i = 0; i < 4; i++)
#pragma unroll
        for (int j = 0; j < 4; j++) acc[i][j] = (f32x4){0.f, 0.f, 0.f, 0.f};

    const float* kbase = keys + (size_t)d.a * NMEM * DIM;

    for (int k0 = 0; k0 < DIM; k0 += 32) {
        {   // stage Q tile: 128 rows x 32 k (2 threads/row, fp32->bf16 cvt)
            int r = tid >> 1, h = tid & 1;
            const float4* src = (const float4*)(qn + (size_t)rows[r] * DIM + k0 + h * 16);
            float4 v0 = src[0], v1 = src[1], v2 = src[2], v3 = src[3];
            BF8 p0, p1;
            p0.v[0] = (__bf16)v0.x; p0.v[1] = (__bf16)v0.y;
            p0.v[2] = (__bf16)v0.z; p0.v[3] = (__bf16)v0.w;
            p0.v[4] = (__bf16)v1.x; p0.v[5] = (__bf16)v1.y;
            p0.v[6] = (__bf16)v1.z; p0.v[7] = (__bf16)v1.w;
            p1.v[0] = (__bf16)v2.x; p1.v[1] = (__bf16)v2.y;
            p1.v[2] = (__bf16)v2.z; p1.v[3] = (__bf16)v2.w;
            p1.v[4] = (__bf16)v3.x; p1.v[5] = (__bf16)v3.y;
            p1.v[6] = (__bf16)v3.z; p1.v[7] = (__bf16)v3.w;
            *(uint4*)&Qs[r][h * 16]     = p0.u;
            *(uint4*)&Qs[r][h * 16 + 8] = p1.u;
        }
        {   // stage K tile: 128 cols x 32 k
            int n = tid >> 1, h = tid & 1;
            const float4* src = (const float4*)(kbase + (size_t)(n0 + n) * DIM + k0 + h * 16);
            float4 v0 = src[0], v1 = src[1], v2 = src[2], v3 = src[3];
            BF8 p0, p1;
            p0.v[0] = (__bf16)v0.x; p0.v[1] = (__bf16)v0.y;
            p0.v[2] = (__bf16)v0.z; p0.v[3] = (__bf16)v0.w;
            p0.v[4] = (__bf16)v1.x; p0.v[5] = (__bf16)v1.y;
            p0.v[6] = (__bf16)v1.z; p0.v[7] = (__bf16)v1.w;
            p1.v[0] = (__bf16)v2.x; p1.v[1] = (__bf16)v2.y;
            p1.v[2] = (__bf16)v2.z; p1.v[3] = (__bf16)v2.w;
            p1.v[4] = (__bf16)v3.x; p1.v[5] = (__bf16)v3.y;
            p1.v[6] = (__bf16)v3.z; p1.v[7] = (__bf16)v3.w;
            *(uint4*)&Ks[n][h * 16]     = p0.u;
            *(uint4*)&Ks[n][h * 16 + 8] = p1.u;
        }
        __syncthreads();
        uint4 kf[4], qf[4];
#pragma unroll
        for (int m = 0; m < 4; m++)
            kf[m] = *(const uint4*)&Ks[wn * 64 + m * 16 + r15][g * 8];
#pragma unroll
        for (int m = 0; m < 4; m++)
            qf[m] = *(const uint4*)&Qs[wq * 64 + m * 16 + r15][g * 8];
#pragma unroll
        for (int i = 0; i < 4; i++)
#pragma unroll
            for (int j = 0; j < 4; j++)
                acc[i][j] = mfma_bf16(kf[i], qf[j], acc[i][j]);
        __syncthreads();
    }

    // epilogue: D[n][q]; lane holds col q = r15, rows n = g*4+reg per frag.
    int sbase = d.s0 - chunk_row0;
#pragma unroll
    for (int j = 0; j < 4; j++) {
        int q = wq * 64 + j * 16 + r15;
        if (q < d.nvalid) {
            unsigned short* orow = simsb + (size_t)(sbase + q) * NMEM + n0;
#pragma unroll
            for (int i = 0; i < 4; i++) {
                int nb = wn * 64 + i * 16 + g * 4;
                float4 iv = *(const float4*)(inv_kn + (size_t)d.a * NMEM + n0 + nb);
                __bf16 e0 = (__bf16)(acc[i][j][0] * iv.x);
                __bf16 e1 = (__bf16)(acc[i][j][1] * iv.y);
                __bf16 e2 = (__bf16)(acc[i][j][2] * iv.z);
                __bf16 e3 = (__bf16)(acc[i][j][3] * iv.w);
                ushort4 o;
                o.x = __builtin_bit_cast(unsigned short, e0);
                o.y = __builtin_bit_cast(unsigned short, e1);
                o.z = __builtin_bit_cast(unsigned short, e2);
                o.w = __builtin_bit_cast(unsigned short, e3);
                *(ushort4*)(orow + nb) = o;
            }
        }
    }
}

// ---------------------------------------------------------------------------
// NEW k_topk: radix screen on bf16 approx sims to >=MSEL candidates (superset
// of true top-50 with ~20x worst-case margin), then EXACT fp32 recompute per
// candidate with the bit-identical fmaf chain (k ascending, acc*inv) that the
// old k_gemm used -> identical selected set, identical values, identical
// softmax/gather output.
__global__ __launch_bounds__(256) void k_topk(
    const unsigned short* __restrict__ simsb,
    const int* __restrict__ sorted_b, const int* __restrict__ sorted_a,
    int chunk_row0,
    const float* __restrict__ qn, const float* __restrict__ keys,
    const float* __restrict__ inv_kn,
    const float* __restrict__ memv, float* __restrict__ cur_next) {
    int tid = threadIdx.x;
    int s = chunk_row0 + blockIdx.x;
    int b = sorted_b[s], a = sorted_a[s];
    const unsigned short* row = simsb + (size_t)blockIdx.x * NMEM;

    __shared__ unsigned hist[256];
    __shared__ unsigned sh_sel;
    __shared__ int sh_need;
    __shared__ unsigned cnum;
    __shared__ int   cidx[RCAP];
    __shared__ float cval[RCAP];
    __shared__ float qs[DIM];
    __shared__ float selw[TOPK];
    __shared__ int   seli[TOPK];

    // cache full bf16 row in registers: 8 uint4 (64 u16) per thread
    uint4 rr[8];
#pragma unroll
    for (int c = 0; c < 8; c++) rr[c] = ((const uint4*)row)[c * 256 + tid];

    // stage q row (fp32, broadcast-read later)
    qs[tid]       = qn[(size_t)b * DIM + tid];
    qs[tid + 256] = qn[(size_t)b * DIM + tid + 256];

    hist[tid] = 0;
    if (tid == 0) cnum = 0;
    __syncthreads();
    // radix screen pass 0: top byte of 16-bit ordered key
#pragma unroll
    for (int c = 0; c < 8; c++) {
        unsigned uu[4] = {rr[c].x, rr[c].y, rr[c].z, rr[c].w};
#pragma unroll
        for (int q2 = 0; q2 < 4; q2++) {
            atomicAdd(&hist[fmap16(uu[q2] & 0xFFFFu) >> 8], 1u);
            atomicAdd(&hist[fmap16(uu[q2] >> 16) >> 8], 1u);
        }
    }
    __syncthreads();
    if (tid == 0) {
        int need = MSEL; unsigned bsel = 0;
        for (int bb = 255; bb >= 0; bb--) {
            int c = (int)hist[bb];
            if (c >= need) { bsel = (unsigned)bb; break; }
            need -= c;
        }
        sh_sel = bsel; sh_need = need;
    }
    __syncthreads();
    unsigned b0 = sh_sel;
    hist[tid] = 0;
    __syncthreads();
    // pass 1: low byte among top-byte == b0
#pragma unroll
    for (int c = 0; c < 8; c++) {
        unsigned uu[4] = {rr[c].x, rr[c].y, rr[c].z, rr[c].w};
#pragma unroll
        for (int q2 = 0; q2 < 4; q2++) {
            unsigned k0 = fmap16(uu[q2] & 0xFFFFu);
            unsigned k1 = fmap16(uu[q2] >> 16);
            if ((k0 >> 8) == b0) atomicAdd(&hist[k0 & 255], 1u);
            if ((k1 >> 8) == b0) atomicAdd(&hist[k1 & 255], 1u);
        }
    }
    __syncthreads();
    if (tid == 0) {
        int need = sh_need; unsigned lsel = 0;
        for (int bb = 255; bb >= 0; bb--) {
            int c = (int)hist[bb];
            if (c >= need) { lsel = (unsigned)bb; break; }
            need -= c;
        }
        sh_sel = (b0 << 8) | lsel;
    }
    __syncthreads();
    unsigned tau16 = sh_sel;

    // collect candidate indices with key16 >= tau16 (>= MSEL incl. ties)
#pragma unroll
    for (int c = 0; c < 8; c++) {
        unsigned uu[4] = {rr[c].x, rr[c].y, rr[c].z, rr[c].w};
#pragma unroll
        for (int q2 = 0; q2 < 4; q2++) {
#pragma unroll
            for (int hh = 0; hh < 2; hh++) {
                unsigned u16v = hh ? (uu[q2] >> 16) : (uu[q2] & 0xFFFFu);
                if (fmap16(u16v) >= tau16) {
                    unsigned p = atomicAdd(&cnum, 1u);
                    if (p < RCAP) cidx[p] = (c * 256 + tid) * 8 + q2 * 2 + hh;
                }
            }
        }
    }
    __syncthreads();
    int ncand = (int)cnum; if (ncand > RCAP) ncand = RCAP;

    // exact fp32 recompute: bit-identical chain to the reference k_gemm
    // (acc = fma(q_k, key_k, acc), k strictly ascending; then * inv once).
    const float* kbase = keys + (size_t)a * NMEM * DIM;
    const float* invp  = inv_kn + (size_t)a * NMEM;
    for (int i = tid; i < ncand; i += 256) {
        int n = cidx[i];
        const float4* kr = (const float4*)(kbase + (size_t)n * DIM);
        float acc = 0.f;
#pragma unroll 8
        for (int k4 = 0; k4 < DIM / 4; k4++) {
            float4 v = kr[k4];
            acc = fmaf(qs[k4 * 4 + 0], v.x, acc);
            acc = fmaf(qs[k4 * 4 + 1], v.y, acc);
            acc = fmaf(qs[k4 * 4 + 2], v.z, acc);
            acc = fmaf(qs[k4 * 4 + 3], v.w, acc);
        }
        cval[i] = acc * invp[n];
    }
    __syncthreads();

    // exact rank select among candidates (f32 desc, index asc) — verbatim
    for (int i = tid; i < ncand; i += 256) {
        float si = cval[i]; int ni = cidx[i];
        int rank = 0;
        for (int j = 0; j < ncand; j++) {
            float sj = cval[j];
            rank += (sj > si) || (sj == si && cidx[j] < ni);
        }
        if (rank < TOPK) { selw[rank] = si; seli[rank] = ni; }
    }
    __syncthreads();
    if (tid == 0) {
        float mx = selw[0];
        for (int i = 1; i < TOPK; i++) mx = fmaxf(mx, selw[i]);
        float ssum = 0.f;
        for (int i = 0; i < TOPK; i++) { float e = expf(selw[i] - mx); selw[i] = e; ssum += e; }
        float inv = 1.0f / ssum;
        for (int i = 0; i < TOPK; i++) selw[i] *= inv;
    }
    __syncthreads();

    const float* mv = memv + (size_t)a * NMEM * DIM;
    float acc0 = 0.f, acc1 = 0.f;
#pragma unroll 10
    for (int i = 0; i < TOPK; i++) {
        const float* vr = mv + (size_t)seli[i] * DIM;
        float wgt = selw[i];
        acc0 += wgt * vr[tid];
        acc1 += wgt * vr[tid + 256];
    }
    float* o = cur_next + (size_t)b * DIM;
    o[tid] = acc0;
    o[tid + 256] = acc1;
}

// ---------------------------------------------------------------------------
// VERBATIM k_mlp.
__global__ __launch_bounds__(256) void k_mlp(
    const float* __restrict__ x,
    const float* __restrict__ W1, const float* __restrict__ b1,
    const float* __restrict__ W2, const float* __restrict__ b2,
    const float* __restrict__ W3, const float* __restrict__ b3,
    float* __restrict__ out, int out_off, int out_stride) {
    int w = threadIdx.x >> 6, lane = threadIdx.x & 63;
    int b = blockIdx.x * 4 + w;
    __shared__ float xs[4][DIM];
    __shared__ float h1s[4][H1N];
    const float* xr = x + (size_t)b * DIM;
#pragma unroll
    for (int i = 0; i < 2; i++) {
        float4 v = *(const float4*)(xr + (lane + i * 64) * 4);
        *(float4*)&xs[w][(lane + i * 64) * 4] = v;
    }
    __syncthreads();
    float a0 = b1[lane], a1 = b1[lane + 64], a2 = b1[lane + 128], a3 = b1[lane + 192];
    for (int k = 0; k < DIM; k++) {
        float xv = xs[w][k];
        const float* wr = W1 + k * H1N;
        a0 += xv * wr[lane];
        a1 += xv * wr[lane + 64];
        a2 += xv * wr[lane + 128];
        a3 += xv * wr[lane + 192];
    }
    h1s[w][lane]       = (a0 > 0.f) ? a0 : expm1f(a0);
    h1s[w][lane + 64]  = (a1 > 0.f) ? a1 : expm1f(a1);
    h1s[w][lane + 128] = (a2 > 0.f) ? a2 : expm1f(a2);
    h1s[w][lane + 192] = (a3 > 0.f) ? a3 : expm1f(a3);
    __syncthreads();
    float c0 = b2[lane], c1 = b2[lane + 64];
    for (int k = 0; k < H1N; k++) {
        float hv = h1s[w][k];
        c0 += hv * W2[k * H2N + lane];
        c1 += hv * W2[k * H2N + lane + 64];
    }
    c0 = ((c0 > 0.f) ? c0 : expm1f(c0)) * W3[lane];
    c1 = ((c1 > 0.f) ? c1 : expm1f(c1)) * W3[lane + 64];
    float ssum = c0 + c1;
    for (int o = 32; o; o >>= 1) ssum += __shfl_down(ssum, o);
    if (lane == 0) out[out_off + b * out_stride] = ssum + b3[0];
}

// ---------------------------------------------------------------------------
extern "C" void kernel_launch(void* const* d_in, const int* in_sizes, int n_in,
                              void* d_out, int out_size, void* d_ws, size_t ws_size,
                              hipStream_t stream) {
    const float* emb  = (const float*)d_in[0];
    const float* keys = (const float*)d_in[1];
    const float* memv = (const float*)d_in[2];
    const float* W1 = (const float*)d_in[3];
    const float* b1 = (const float*)d_in[4];
    const float* W2 = (const float*)d_in[5];
    const float* b2 = (const float*)d_in[6];
    const float* W3 = (const float*)d_in[7];
    const float* b3 = (const float*)d_in[8];
    const int* actions = (const int*)d_in[9];
    float* out = (float*)d_out;

    char* ws = (char*)d_ws;
    size_t off = 0;
    auto alloc = [&](size_t bytes) -> void* {
        void* p = ws + off;
        off = (off + bytes + 255) & ~(size_t)255;
        return p;
    };
    float* inv_kn  = (float*)alloc(sizeof(float) * A_CNT * NMEM);
    float* qn      = (float*)alloc(sizeof(float) * NB * DIM);
    float* curA    = (float*)alloc(sizeof(float) * NB * DIM);
    float* curB    = (float*)alloc(sizeof(float) * NB * DIM);
    int* sorted_b  = (int*)alloc(sizeof(int) * NB);
    int* sorted_a  = (int*)alloc(sizeof(int) * NB);
    TileDesc* descs = (TileDesc*)alloc(sizeof(TileDesc) * 64);
    size_t rem = (ws_size > off) ? (ws_size - off) : 0;
    int CB = 256;
    if (rem >= sizeof(unsigned short) * (size_t)1024 * NMEM + 4096) CB = 1024;
    else if (rem >= sizeof(unsigned short) * (size_t)512 * NMEM + 4096) CB = 512;
    unsigned short* simsb = (unsigned short*)alloc(sizeof(unsigned short) * (size_t)CB * NMEM);
    int nch = NB / CB;
    int maxd = CB / TM + A_CNT;

    k_inv_norm<<<dim3(A_CNT * NMEM / 4), dim3(256), 0, stream>>>(keys, inv_kn);
    k_mlp<<<dim3(NB / 4), dim3(256), 0, stream>>>(emb, W1, b1, W2, b2, W3, b3, out, 0, 1);

    const float* cur = emb;
    float* nxt = curA;
    for (int t = 0; t < NSTEPS; t++) {
        k_group<<<dim3(1), dim3(64), 0, stream>>>(actions, t, sorted_b, sorted_a, descs, CB, maxd, nch);
        k_qnorm<<<dim3(NB), dim3(256), 0, stream>>>(cur, qn);
        for (int c = 0; c < nch; c++) {
            k_screen<<<dim3(NMEM / TN, maxd), dim3(256), 0, stream>>>(
                qn, keys, inv_kn, sorted_b, descs + c * maxd, c * CB, simsb);
            k_topk<<<dim3(CB), dim3(256), 0, stream>>>(
                simsb, sorted_b, sorted_a, c * CB, qn, keys, inv_kn, memv, nxt);
        }
        k_mlp<<<dim3(NB / 4), dim3(256), 0, stream>>>(nxt, W1, b1, W2, b2, W3, b3, out, NB + t, NSTEPS);
        cur = nxt;
        nxt = (nxt == curA) ? curB : curA;
    }
}

// Round 2
// 1323.963 us; speedup vs baseline: 1.7749x; 1.0948x over previous
//
#include <hip/hip_runtime.h>

#define A_CNT   5
#define NB      1024
#define DIM     512
#define NMEM    16384
#define TOPK    50
#define NSTEPS  5
#define H1N     256
#define H2N     128

#define TM      128
#define TN      128
#define MSEL    100     // screen candidates per row (slack over TOPK=50)
#define RCAP    512     // candidate buffer cap

struct TileDesc { int a; int s0; int nvalid; int pad; };

typedef __bf16 bf16x8 __attribute__((ext_vector_type(8)));
typedef short  s16x8  __attribute__((ext_vector_type(8)));
typedef float  f32x4  __attribute__((ext_vector_type(4)));

// SFINAE hedge for the bf16 MFMA builtin operand type across toolchains.
template <typename T>
__device__ __forceinline__ auto mfma_try(T a, T b, f32x4 c, int)
    -> decltype(__builtin_amdgcn_mfma_f32_16x16x32_bf16(a, b, c, 0, 0, 0)) {
    return __builtin_amdgcn_mfma_f32_16x16x32_bf16(a, b, c, 0, 0, 0);
}
template <typename T>
__device__ __forceinline__ f32x4 mfma_try(T a, T b, f32x4 c, long) {
    return __builtin_amdgcn_mfma_f32_16x16x32_bf16(
        __builtin_bit_cast(s16x8, a), __builtin_bit_cast(s16x8, b), c, 0, 0, 0);
}
__device__ __forceinline__ f32x4 mfma_bf16(uint4 a, uint4 b, f32x4 c) {
    return mfma_try(__builtin_bit_cast(bf16x8, a), __builtin_bit_cast(bf16x8, b), c, 0);
}

union BF8 { bf16x8 v; uint4 u; };

// async global->LDS, 16B per lane. LDS dest must be wave-uniform base + lane*16
// (ours is: dest = base + f*16, f = i*256 + tid). Int-mediated addrspace casts:
// generic->AS3 is a truncation (flat LDS addr low 32 bits == ds offset).
__device__ __forceinline__ void gload_lds16(const void* g, void* l) {
    __builtin_amdgcn_global_load_lds(
        (const __attribute__((address_space(1))) void*)(unsigned long long)g,
        (__attribute__((address_space(3))) void*)(unsigned)(unsigned long long)l,
        16, 0, 0);
}

// ---------------------------------------------------------------------------
// k_prep_keys: fused inv-norm (VERBATIM reduction chain from k_inv_norm) +
// one-time fp32->bf16 key conversion. Same (__bf16) casts the old in-loop
// staging used -> bit-identical bf16 key values.
__global__ __launch_bounds__(256) void k_prep_keys(const float* __restrict__ keys,
                                                   float* __restrict__ inv,
                                                   unsigned short* __restrict__ kb) {
    int row  = blockIdx.x * 4 + (threadIdx.x >> 6);
    int lane = threadIdx.x & 63;
    const float* p = keys + (size_t)row * DIM;
    float ss = 0.f;
    for (int i = lane; i < DIM; i += 64) { float v = p[i]; ss += v * v; }
    for (int o = 32; o; o >>= 1) ss += __shfl_down(ss, o);
    ss = __shfl(ss, 0);
    if (lane == 0) inv[row] = 1.0f / (sqrtf(ss) + 1e-8f);
    // bf16 convert: 8 contiguous elems per lane (reads hit L1/L2, HBM once)
    const float4* s4 = (const float4*)(p + lane * 8);
    float4 v0 = s4[0], v1 = s4[1];
    BF8 pk;
    pk.v[0] = (__bf16)v0.x; pk.v[1] = (__bf16)v0.y;
    pk.v[2] = (__bf16)v0.z; pk.v[3] = (__bf16)v0.w;
    pk.v[4] = (__bf16)v1.x; pk.v[5] = (__bf16)v1.y;
    pk.v[6] = (__bf16)v1.z; pk.v[7] = (__bf16)v1.w;
    *(uint4*)(kb + (size_t)row * DIM + lane * 8) = pk.u;
}

// k_qnorm: VERBATIM fp32 path + added bf16 mirror write (cast of the exact
// same fp32 value the old k_screen staging converted).
__global__ __launch_bounds__(256) void k_qnorm(const float* __restrict__ x,
                                               float* __restrict__ qn,
                                               unsigned short* __restrict__ qb) {
    int row = blockIdx.x, tid = threadIdx.x;
    const float* p = x + (size_t)row * DIM;
    float ss = 0.f;
    for (int i = tid; i < DIM; i += 256) { float v = p[i]; ss += v * v; }
    for (int o = 32; o; o >>= 1) ss += __shfl_down(ss, o);
    __shared__ float w4[4];
    if ((tid & 63) == 0) w4[tid >> 6] = ss;
    __syncthreads();
    float tot = w4[0] + w4[1] + w4[2] + w4[3];
    float s = 1.0f / (sqrtf(tot) + 1e-8f);
    float* q = qn + (size_t)row * DIM;
    unsigned short* qbr = qb + (size_t)row * DIM;
    for (int i = tid; i < DIM; i += 256) {
        float v = p[i] * s;
        q[i] = v;
        __bf16 h = (__bf16)v;
        qbr[i] = __builtin_bit_cast(unsigned short, h);
    }
}

// ROUND-1 VERBATIM.
__global__ void k_group(const int* __restrict__ actions, int t,
                        int* __restrict__ sorted_b, int* __restrict__ sorted_a,
                        TileDesc* __restrict__ descs, int cb, int maxd, int nch) {
    int lane = threadIdx.x;  // blockDim = 64
    for (int i = lane; i < nch * maxd; i += 64) descs[i].a = -1;
    __shared__ int gs[A_CNT + 1];
    int out_pos = 0;
    for (int a = 0; a < A_CNT; a++) {
        if (lane == 0) gs[a] = out_pos;
        for (int c = 0; c < NB; c += 64) {
            int b = c + lane;
            int act = actions[b * NSTEPS + t];
            unsigned long long m = __ballot(act == a);
            int rank = __popcll(m & ((1ULL << lane) - 1ULL));
            if (act == a) { sorted_b[out_pos + rank] = b; sorted_a[out_pos + rank] = a; }
            out_pos += __popcll(m);
        }
    }
    if (lane == 0) {
        gs[A_CNT] = NB;
        int ndc[4] = {0, 0, 0, 0};
        for (int a = 0; a < A_CNT; a++) {
            int s = gs[a], e = gs[a + 1];
            while (s < e) {
                int c = s / cb;
                int lim = min(e, (c + 1) * cb);
                int len = min(TM, lim - s);
                TileDesc d; d.a = a; d.s0 = s; d.nvalid = len; d.pad = 0;
                descs[c * maxd + ndc[c]++] = d;
                s += len;
            }
        }
    }
}

// ---------------------------------------------------------------------------
// k_screen v2: m97 structure — pre-converted bf16 operands, global_load_lds
// width-16 staging into linear [128][32] LDS (b128 frag reads are at the bank
// floor), 2 barriers per K-step, identical MFMA order -> simsb bit-identical
// to the previous round.
__global__ __launch_bounds__(256) void k_screen(
    const unsigned short* __restrict__ qb, const unsigned short* __restrict__ kb,
    const float* __restrict__ inv_kn, const int* __restrict__ sorted_b,
    const TileDesc* __restrict__ descs, int chunk_row0,
    unsigned short* __restrict__ simsb) {
    TileDesc d = descs[blockIdx.y];
    if (d.a < 0) return;
    int tid = threadIdx.x;
    int n0 = blockIdx.x * TN;
    __shared__ __align__(16) unsigned short Qs[TM][32];
    __shared__ __align__(16) unsigned short Ks[TN][32];
    __shared__ int rows[TM];
    if (tid < TM) rows[tid] = sorted_b[d.s0 + min(tid, d.nvalid - 1)];
    __syncthreads();

    int w = tid >> 6, lane = tid & 63;
    int g = lane >> 4, r15 = lane & 15;
    int wq = w >> 1, wn = w & 1;

    // fixed (row, chunk) per thread across the K loop; 16B per lane per issue
    int srow = tid >> 2, schunk = (tid & 3) * 8;
    const unsigned short* kbase = kb + (size_t)d.a * NMEM * DIM;
    const unsigned short* q0 = qb + (size_t)rows[srow] * DIM + schunk;
    const unsigned short* q1 = qb + (size_t)rows[64 + srow] * DIM + schunk;
    const unsigned short* k0p = kbase + (size_t)(n0 + srow) * DIM + schunk;
    const unsigned short* k1p = kbase + (size_t)(n0 + 64 + srow) * DIM + schunk;
    char* ldsQ = (char*)&Qs[0][0] + tid * 16;
    char* ldsK = (char*)&Ks[0][0] + tid * 16;

    f32x4 acc[4][4];
#pragma unroll
    for (int i = 0; i < 4; i++)
#pragma unroll
        for (int j = 0; j < 4; j++) acc[i][j] = (f32x4){0.f, 0.f, 0.f, 0.f};

    for (int k0 = 0; k0 < DIM; k0 += 32) {
        gload_lds16(q0 + k0,  ldsQ);
        gload_lds16(q1 + k0,  ldsQ + 4096);
        gload_lds16(k0p + k0, ldsK);
        gload_lds16(k1p + k0, ldsK + 4096);
        __syncthreads();   // compiler drains vmcnt before s_barrier
        uint4 kf[4], qf[4];
#pragma unroll
        for (int m = 0; m < 4; m++)
            kf[m] = *(const uint4*)&Ks[wn * 64 + m * 16 + r15][g * 8];
#pragma unroll
        for (int m = 0; m < 4; m++)
            qf[m] = *(const uint4*)&Qs[wq * 64 + m * 16 + r15][g * 8];
#pragma unroll
        for (int i = 0; i < 4; i++)
#pragma unroll
            for (int j = 0; j < 4; j++)
                acc[i][j] = mfma_bf16(kf[i], qf[j], acc[i][j]);
        __syncthreads();
    }

    // epilogue: D[n][q]; lane holds col q = r15, rows n = g*4+reg per frag.
    int sbase = d.s0 - chunk_row0;
#pragma unroll
    for (int j = 0; j < 4; j++) {
        int q = wq * 64 + j * 16 + r15;
        if (q < d.nvalid) {
            unsigned short* orow = simsb + (size_t)(sbase + q) * NMEM + n0;
#pragma unroll
            for (int i = 0; i < 4; i++) {
                int nb = wn * 64 + i * 16 + g * 4;
                float4 iv = *(const float4*)(inv_kn + (size_t)d.a * NMEM + n0 + nb);
                __bf16 e0 = (__bf16)(acc[i][j][0] * iv.x);
                __bf16 e1 = (__bf16)(acc[i][j][1] * iv.y);
                __bf16 e2 = (__bf16)(acc[i][j][2] * iv.z);
                __bf16 e3 = (__bf16)(acc[i][j][3] * iv.w);
                ushort4 o;
                o.x = __builtin_bit_cast(unsigned short, e0);
                o.y = __builtin_bit_cast(unsigned short, e1);
                o.z = __builtin_bit_cast(unsigned short, e2);
                o.w = __builtin_bit_cast(unsigned short, e3);
                *(ushort4*)(orow + nb) = o;
            }
        }
    }
}

// ---------------------------------------------------------------------------
// k_topk v2: binary-search threshold (replaces LDS-atomic radix histograms —
// identical tau: largest 16-bit t with count(key16 >= t) >= MSEL), then the
// VERBATIM exact fp32 recompute / rank select / softmax / gather.
__global__ __launch_bounds__(256) void k_topk(
    const unsigned short* __restrict__ simsb,
    const int* __restrict__ sorted_b, const int* __restrict__ sorted_a,
    int chunk_row0,
    const float* __restrict__ qn, const float* __restrict__ keys,
    const float* __restrict__ inv_kn,
    const float* __restrict__ memv, float* __restrict__ cur_next) {
    int tid = threadIdx.x;
    int s = chunk_row0 + blockIdx.x;
    int b = sorted_b[s], a = sorted_a[s];
    const unsigned short* row = simsb + (size_t)blockIdx.x * NMEM;

    __shared__ unsigned cnum;
    __shared__ int   cidx[RCAP];
    __shared__ float cval[RCAP];
    __shared__ float qs[DIM];
    __shared__ float selw[TOPK];
    __shared__ int   seli[TOPK];
    __shared__ int   wred[2][4];

    // cache full bf16 row: 8 uint4 (64 u16) per thread; fmap16 in place
    // (packed: per-half XOR mask = 0x8000 | sign*0x7FFF).
    uint4 rr[8];
#pragma unroll
    for (int c = 0; c < 8; c++) {
        uint4 v = ((const uint4*)row)[c * 256 + tid];
        unsigned s0 = (v.x >> 15) & 0x00010001u;
        unsigned s1 = (v.y >> 15) & 0x00010001u;
        unsigned s2 = (v.z >> 15) & 0x00010001u;
        unsigned s3 = (v.w >> 15) & 0x00010001u;
        v.x ^= 0x80008000u | (s0 * 0x7FFFu);
        v.y ^= 0x80008000u | (s1 * 0x7FFFu);
        v.z ^= 0x80008000u | (s2 * 0x7FFFu);
        v.w ^= 0x80008000u | (s3 * 0x7FFFu);
        rr[c] = v;
    }

    qs[tid]       = qn[(size_t)b * DIM + tid];
    qs[tid + 256] = qn[(size_t)b * DIM + tid + 256];
    if (tid == 0) cnum = 0;

    // binary search: invariant count(>=lo) >= MSEL, count(>=hi) < MSEL
    unsigned lo = 0, hi = 65536;
    for (int it = 0; it < 16; ++it) {
        unsigned mid = (lo + hi) >> 1;
        int cnt = 0;
#pragma unroll
        for (int c = 0; c < 8; c++) {
            unsigned w0 = rr[c].x, w1 = rr[c].y, w2 = rr[c].z, w3 = rr[c].w;
            cnt += ((w0 & 0xFFFFu) >= mid) + ((w0 >> 16) >= mid);
            cnt += ((w1 & 0xFFFFu) >= mid) + ((w1 >> 16) >= mid);
            cnt += ((w2 & 0xFFFFu) >= mid) + ((w2 >> 16) >= mid);
            cnt += ((w3 & 0xFFFFu) >= mid) + ((w3 >> 16) >= mid);
        }
        for (int o = 32; o; o >>= 1) cnt += __shfl_down(cnt, o);
        if ((tid & 63) == 0) wred[it & 1][tid >> 6] = cnt;
        __syncthreads();
        int tot = wred[it & 1][0] + wred[it & 1][1] + wred[it & 1][2] + wred[it & 1][3];
        if ((unsigned)tot >= MSEL) lo = mid; else hi = mid;
    }
    unsigned tau16 = lo;   // uniform across block

    // collect candidate indices with fmapped key16 >= tau16
#pragma unroll
    for (int c = 0; c < 8; c++) {
        unsigned uu[4] = {rr[c].x, rr[c].y, rr[c].z, rr[c].w};
#pragma unroll
        for (int q2 = 0; q2 < 4; q2++) {
#pragma unroll
            for (int hh = 0; hh < 2; hh++) {
                unsigned u16v = hh ? (uu[q2] >> 16) : (uu[q2] & 0xFFFFu);
                if (u16v >= tau16) {
                    unsigned p = atomicAdd(&cnum, 1u);
                    if (p < RCAP) cidx[p] = (c * 256 + tid) * 8 + q2 * 2 + hh;
                }
            }
        }
    }
    __syncthreads();
    int ncand = (int)cnum; if (ncand > RCAP) ncand = RCAP;

    // exact fp32 recompute: bit-identical chain (fmaf, k ascending; * inv once)
    const float* kbase = keys + (size_t)a * NMEM * DIM;
    const float* invp  = inv_kn + (size_t)a * NMEM;
    for (int i = tid; i < ncand; i += 256) {
        int n = cidx[i];
        const float4* kr = (const float4*)(kbase + (size_t)n * DIM);
        float acc = 0.f;
#pragma unroll 8
        for (int k4 = 0; k4 < DIM / 4; k4++) {
            float4 v = kr[k4];
            acc = fmaf(qs[k4 * 4 + 0], v.x, acc);
            acc = fmaf(qs[k4 * 4 + 1], v.y, acc);
            acc = fmaf(qs[k4 * 4 + 2], v.z, acc);
            acc = fmaf(qs[k4 * 4 + 3], v.w, acc);
        }
        cval[i] = acc * invp[n];
    }
    __syncthreads();

    // exact rank select among candidates (f32 desc, index asc) — verbatim
    for (int i = tid; i < ncand; i += 256) {
        float si = cval[i]; int ni = cidx[i];
        int rank = 0;
        for (int j = 0; j < ncand; j++) {
            float sj = cval[j];
            rank += (sj > si) || (sj == si && cidx[j] < ni);
        }
        if (rank < TOPK) { selw[rank] = si; seli[rank] = ni; }
    }
    __syncthreads();
    if (tid == 0) {
        float mx = selw[0];
        for (int i = 1; i < TOPK; i++) mx = fmaxf(mx, selw[i]);
        float ssum = 0.f;
        for (int i = 0; i < TOPK; i++) { float e = expf(selw[i] - mx); selw[i] = e; ssum += e; }
        float inv = 1.0f / ssum;
        for (int i = 0; i < TOPK; i++) selw[i] *= inv;
    }
    __syncthreads();

    const float* mv = memv + (size_t)a * NMEM * DIM;
    float acc0 = 0.f, acc1 = 0.f;
#pragma unroll 10
    for (int i = 0; i < TOPK; i++) {
        const float* vr = mv + (size_t)seli[i] * DIM;
        float wgt = selw[i];
        acc0 += wgt * vr[tid];
        acc1 += wgt * vr[tid + 256];
    }
    float* o = cur_next + (size_t)b * DIM;
    o[tid] = acc0;
    o[tid + 256] = acc1;
}

// ---------------------------------------------------------------------------
// VERBATIM k_mlp.
__global__ __launch_bounds__(256) void k_mlp(
    const float* __restrict__ x,
    const float* __restrict__ W1, const float* __restrict__ b1,
    const float* __restrict__ W2, const float* __restrict__ b2,
    const float* __restrict__ W3, const float* __restrict__ b3,
    float* __restrict__ out, int out_off, int out_stride) {
    int w = threadIdx.x >> 6, lane = threadIdx.x & 63;
    int b = blockIdx.x * 4 + w;
    __shared__ float xs[4][DIM];
    __shared__ float h1s[4][H1N];
    const float* xr = x + (size_t)b * DIM;
#pragma unroll
    for (int i = 0; i < 2; i++) {
        float4 v = *(const float4*)(xr + (lane + i * 64) * 4);
        *(float4*)&xs[w][(lane + i * 64) * 4] = v;
    }
    __syncthreads();
    float a0 = b1[lane], a1 = b1[lane + 64], a2 = b1[lane + 128], a3 = b1[lane + 192];
    for (int k = 0; k < DIM; k++) {
        float xv = xs[w][k];
        const float* wr = W1 + k * H1N;
        a0 += xv * wr[lane];
        a1 += xv * wr[lane + 64];
        a2 += xv * wr[lane + 128];
        a3 += xv * wr[lane + 192];
    }
    h1s[w][lane]       = (a0 > 0.f) ? a0 : expm1f(a0);
    h1s[w][lane + 64]  = (a1 > 0.f) ? a1 : expm1f(a1);
    h1s[w][lane + 128] = (a2 > 0.f) ? a2 : expm1f(a2);
    h1s[w][lane + 192] = (a3 > 0.f) ? a3 : expm1f(a3);
    __syncthreads();
    float c0 = b2[lane], c1 = b2[lane + 64];
    for (int k = 0; k < H1N; k++) {
        float hv = h1s[w][k];
        c0 += hv * W2[k * H2N + lane];
        c1 += hv * W2[k * H2N + lane + 64];
    }
    c0 = ((c0 > 0.f) ? c0 : expm1f(c0)) * W3[lane];
    c1 = ((c1 > 0.f) ? c1 : expm1f(c1)) * W3[lane + 64];
    float ssum = c0 + c1;
    for (int o = 32; o; o >>= 1) ssum += __shfl_down(ssum, o);
    if (lane == 0) out[out_off + b * out_stride] = ssum + b3[0];
}

// ---------------------------------------------------------------------------
extern "C" void kernel_launch(void* const* d_in, const int* in_sizes, int n_in,
                              void* d_out, int out_size, void* d_ws, size_t ws_size,
                              hipStream_t stream) {
    const float* emb  = (const float*)d_in[0];
    const float* keys = (const float*)d_in[1];
    const float* memv = (const float*)d_in[2];
    const float* W1 = (const float*)d_in[3];
    const float* b1 = (const float*)d_in[4];
    const float* W2 = (const float*)d_in[5];
    const float* b2 = (const float*)d_in[6];
    const float* W3 = (const float*)d_in[7];
    const float* b3 = (const float*)d_in[8];
    const int* actions = (const int*)d_in[9];
    float* out = (float*)d_out;

    char* ws = (char*)d_ws;
    size_t off = 0;
    auto alloc = [&](size_t bytes) -> void* {
        void* p = ws + off;
        off = (off + bytes + 255) & ~(size_t)255;
        return p;
    };
    float* inv_kn  = (float*)alloc(sizeof(float) * A_CNT * NMEM);
    float* qn      = (float*)alloc(sizeof(float) * NB * DIM);
    unsigned short* qb = (unsigned short*)alloc(sizeof(unsigned short) * NB * DIM);
    unsigned short* kb = (unsigned short*)alloc(sizeof(unsigned short) * (size_t)A_CNT * NMEM * DIM);
    float* curA    = (float*)alloc(sizeof(float) * NB * DIM);
    float* curB    = (float*)alloc(sizeof(float) * NB * DIM);
    int* sorted_b  = (int*)alloc(sizeof(int) * NB);
    int* sorted_a  = (int*)alloc(sizeof(int) * NB);
    TileDesc* descs = (TileDesc*)alloc(sizeof(TileDesc) * 64);
    size_t rem = (ws_size > off) ? (ws_size - off) : 0;
    int CB = 256;
    if (rem >= sizeof(unsigned short) * (size_t)1024 * NMEM + 4096) CB = 1024;
    else if (rem >= sizeof(unsigned short) * (size_t)512 * NMEM + 4096) CB = 512;
    unsigned short* simsb = (unsigned short*)alloc(sizeof(unsigned short) * (size_t)CB * NMEM);
    int nch = NB / CB;
    int maxd = CB / TM + A_CNT;

    k_prep_keys<<<dim3(A_CNT * NMEM / 4), dim3(256), 0, stream>>>(keys, inv_kn, kb);
    k_mlp<<<dim3(NB / 4), dim3(256), 0, stream>>>(emb, W1, b1, W2, b2, W3, b3, out, 0, 1);

    const float* cur = emb;
    float* nxt = curA;
    for (int t = 0; t < NSTEPS; t++) {
        k_group<<<dim3(1), dim3(64), 0, stream>>>(actions, t, sorted_b, sorted_a, descs, CB, maxd, nch);
        k_qnorm<<<dim3(NB), dim3(256), 0, stream>>>(cur, qn, qb);
        for (int c = 0; c < nch; c++) {
            k_screen<<<dim3(NMEM / TN, maxd), dim3(256), 0, stream>>>(
                qb, kb, inv_kn, sorted_b, descs + c * maxd, c * CB, simsb);
            k_topk<<<dim3(CB), dim3(256), 0, stream>>>(
                simsb, sorted_b, sorted_a, c * CB, qn, keys, inv_kn, memv, nxt);
        }
        k_mlp<<<dim3(NB / 4), dim3(256), 0, stream>>>(nxt, W1, b1, W2, b2, W3, b3, out, NB + t, NSTEPS);
        cur = nxt;
        nxt = (nxt == curA) ? curB : curA;
    }
}

// Round 5
// 1283.525 us; speedup vs baseline: 1.8308x; 1.0315x over previous
//
#include <hip/hip_runtime.h>

#define A_CNT   5
#define NB      1024
#define DIM     512
#define NMEM    16384
#define TOPK    50
#define NSTEPS  5
#define H1N     256
#define H2N     128

#define TM      128
#define TN      128
#define MSEL    100     // screen candidates per row (slack over TOPK=50)
#define RCAP    512     // candidate buffer cap

struct TileDesc { int a; int s0; int nvalid; int pad; };

typedef __bf16 bf16x8 __attribute__((ext_vector_type(8)));
typedef short  s16x8  __attribute__((ext_vector_type(8)));
typedef float  f32x4  __attribute__((ext_vector_type(4)));

// SFINAE hedge for the bf16 MFMA builtin operand type across toolchains.
template <typename T>
__device__ __forceinline__ auto mfma_try(T a, T b, f32x4 c, int)
    -> decltype(__builtin_amdgcn_mfma_f32_16x16x32_bf16(a, b, c, 0, 0, 0)) {
    return __builtin_amdgcn_mfma_f32_16x16x32_bf16(a, b, c, 0, 0, 0);
}
template <typename T>
__device__ __forceinline__ f32x4 mfma_try(T a, T b, f32x4 c, long) {
    return __builtin_amdgcn_mfma_f32_16x16x32_bf16(
        __builtin_bit_cast(s16x8, a), __builtin_bit_cast(s16x8, b), c, 0, 0, 0);
}
__device__ __forceinline__ f32x4 mfma_bf16(uint4 a, uint4 b, f32x4 c) {
    return mfma_try(__builtin_bit_cast(bf16x8, a), __builtin_bit_cast(bf16x8, b), c, 0);
}

union BF8 { bf16x8 v; uint4 u; };

// async global->LDS, 16B per lane (dest = wave-uniform base + lane*16).
__device__ __forceinline__ void gload_lds16(const void* g, void* l) {
    __builtin_amdgcn_global_load_lds(
        (const __attribute__((address_space(1))) void*)(unsigned long long)g,
        (__attribute__((address_space(3))) void*)(unsigned)(unsigned long long)l,
        16, 0, 0);
}

// ---------------------------------------------------------------------------
// k_prep_keys: fused inv-norm (VERBATIM reduction chain) + one-time fp32->bf16
// key conversion.
__global__ __launch_bounds__(256) void k_prep_keys(const float* __restrict__ keys,
                                                   float* __restrict__ inv,
                                                   unsigned short* __restrict__ kb) {
    int row  = blockIdx.x * 4 + (threadIdx.x >> 6);
    int lane = threadIdx.x & 63;
    const float* p = keys + (size_t)row * DIM;
    float ss = 0.f;
    for (int i = lane; i < DIM; i += 64) { float v = p[i]; ss += v * v; }
    for (int o = 32; o; o >>= 1) ss += __shfl_down(ss, o);
    ss = __shfl(ss, 0);
    if (lane == 0) inv[row] = 1.0f / (sqrtf(ss) + 1e-8f);
    const float4* s4 = (const float4*)(p + lane * 8);
    float4 v0 = s4[0], v1 = s4[1];
    BF8 pk;
    pk.v[0] = (__bf16)v0.x; pk.v[1] = (__bf16)v0.y;
    pk.v[2] = (__bf16)v0.z; pk.v[3] = (__bf16)v0.w;
    pk.v[4] = (__bf16)v1.x; pk.v[5] = (__bf16)v1.y;
    pk.v[6] = (__bf16)v1.z; pk.v[7] = (__bf16)v1.w;
    *(uint4*)(kb + (size_t)row * DIM + lane * 8) = pk.u;
}

// k_qnorm (step-0 only): VERBATIM fp32 path + bf16 mirror.
__global__ __launch_bounds__(256) void k_qnorm(const float* __restrict__ x,
                                               float* __restrict__ qn,
                                               unsigned short* __restrict__ qb) {
    int row = blockIdx.x, tid = threadIdx.x;
    const float* p = x + (size_t)row * DIM;
    float ss = 0.f;
    for (int i = tid; i < DIM; i += 256) { float v = p[i]; ss += v * v; }
    for (int o = 32; o; o >>= 1) ss += __shfl_down(ss, o);
    __shared__ float w4[4];
    if ((tid & 63) == 0) w4[tid >> 6] = ss;
    __syncthreads();
    float tot = w4[0] + w4[1] + w4[2] + w4[3];
    float s = 1.0f / (sqrtf(tot) + 1e-8f);
    float* q = qn + (size_t)row * DIM;
    unsigned short* qbr = qb + (size_t)row * DIM;
    for (int i = tid; i < DIM; i += 256) {
        float v = p[i] * s;
        q[i] = v;
        __bf16 h = (__bf16)v;
        qbr[i] = __builtin_bit_cast(unsigned short, h);
    }
}

// k_group_all: all NSTEPS groupings upfront (depends only on actions).
// Body is the ROUND-1 k_group verbatim with t = blockIdx.x.
__global__ void k_group_all(const int* __restrict__ actions,
                            int* __restrict__ sorted_b_all, int* __restrict__ sorted_a_all,
                            TileDesc* __restrict__ descs_all, int cb, int maxd, int nch) {
    int t = blockIdx.x;
    int* sorted_b = sorted_b_all + t * NB;
    int* sorted_a = sorted_a_all + t * NB;
    TileDesc* descs = descs_all + t * (nch * maxd);
    int lane = threadIdx.x;  // blockDim = 64
    for (int i = lane; i < nch * maxd; i += 64) descs[i].a = -1;
    __shared__ int gs[A_CNT + 1];
    int out_pos = 0;
    for (int a = 0; a < A_CNT; a++) {
        if (lane == 0) gs[a] = out_pos;
        for (int c = 0; c < NB; c += 64) {
            int b = c + lane;
            int act = actions[b * NSTEPS + t];
            unsigned long long m = __ballot(act == a);
            int rank = __popcll(m & ((1ULL << lane) - 1ULL));
            if (act == a) { sorted_b[out_pos + rank] = b; sorted_a[out_pos + rank] = a; }
            out_pos += __popcll(m);
        }
    }
    if (lane == 0) {
        gs[A_CNT] = NB;
        int ndc[4] = {0, 0, 0, 0};
        for (int a = 0; a < A_CNT; a++) {
            int s = gs[a], e = gs[a + 1];
            while (s < e) {
                int c = s / cb;
                int lim = min(e, (c + 1) * cb);
                int len = min(TM, lim - s);
                TileDesc d; d.a = a; d.s0 = s; d.nvalid = len; d.pad = 0;
                descs[c * maxd + ndc[c]++] = d;
                s += len;
            }
        }
    }
}

// ---------------------------------------------------------------------------
// k_screen v5: ROUND-2's proven single-buffer 2-barrier loop (sync skeleton
// unchanged) + XOR-swizzled LDS addressing only (linear gload_lds dest,
// pre-swizzled global source chunk, swizzled frag-read column). Fragment
// CONTENTS identical to round 2 -> sims bit-identical. Frag ds_read_b128
// bank conflict: 8-way -> 2-way (free).
__global__ __launch_bounds__(256) void k_screen(
    const unsigned short* __restrict__ qb, const unsigned short* __restrict__ kb,
    const float* __restrict__ inv_kn, const int* __restrict__ sorted_b,
    const TileDesc* __restrict__ descs, int chunk_row0,
    unsigned short* __restrict__ simsb) {
    TileDesc d = descs[blockIdx.x];
    if (d.a < 0) return;
    int tid = threadIdx.x;
    int n0 = blockIdx.y * TN;
    __shared__ __align__(16) unsigned short Qs[TM][32];
    __shared__ __align__(16) unsigned short Ks[TN][32];
    __shared__ int rows[TM];
    if (tid < TM) rows[tid] = sorted_b[d.s0 + min(tid, d.nvalid - 1)];
    __syncthreads();

    int w = tid >> 6, lane = tid & 63;
    int g = lane >> 4, r15 = lane & 15;
    int wq = w >> 1, wn = w & 1;
    int swc = (g ^ ((r15 >> 1) & 3)) * 8;   // swizzled frag column (u16 units)

    // staging: dest slot = tid (linear: phys row tid>>2, phys chunk tid&3).
    // phys chunk c holds logical chunk c ^ s(row), s(row)=(row>>1)&3
    // -> source k-chunk = ((tid&3) ^ ((tid>>3)&3)) * 8.
    // frag rows R = base+m*16+r15 have s(R)=(r15>>1)&3 -> read col swc above.
    int srow = tid >> 2, schunk = ((tid & 3) ^ ((tid >> 3) & 3)) * 8;
    const unsigned short* kbase = kb + (size_t)d.a * NMEM * DIM;
    const unsigned short* q0 = qb + (size_t)rows[srow] * DIM + schunk;
    const unsigned short* q1 = qb + (size_t)rows[64 + srow] * DIM + schunk;
    const unsigned short* k0p = kbase + (size_t)(n0 + srow) * DIM + schunk;
    const unsigned short* k1p = kbase + (size_t)(n0 + 64 + srow) * DIM + schunk;
    char* ldsQ = (char*)&Qs[0][0] + tid * 16;
    char* ldsK = (char*)&Ks[0][0] + tid * 16;

    f32x4 acc[4][4];
#pragma unroll
    for (int i = 0; i < 4; i++)
#pragma unroll
        for (int j = 0; j < 4; j++) acc[i][j] = (f32x4){0.f, 0.f, 0.f, 0.f};

    for (int k0 = 0; k0 < DIM; k0 += 32) {
        gload_lds16(q0 + k0,  ldsQ);
        gload_lds16(q1 + k0,  ldsQ + 4096);
        gload_lds16(k0p + k0, ldsK);
        gload_lds16(k1p + k0, ldsK + 4096);
        __syncthreads();   // drains vmcnt before barrier (round-2 skeleton)
        uint4 kf[4], qf[4];
#pragma unroll
        for (int m = 0; m < 4; m++)
            kf[m] = *(const uint4*)&Ks[wn * 64 + m * 16 + r15][swc];
#pragma unroll
        for (int m = 0; m < 4; m++)
            qf[m] = *(const uint4*)&Qs[wq * 64 + m * 16 + r15][swc];
#pragma unroll
        for (int i = 0; i < 4; i++)
#pragma unroll
            for (int j = 0; j < 4; j++)
                acc[i][j] = mfma_bf16(kf[i], qf[j], acc[i][j]);
        __syncthreads();
    }

    // epilogue: D[n][q]; lane holds col q = r15, rows n = g*4+reg per frag.
    int sbase = d.s0 - chunk_row0;
#pragma unroll
    for (int j = 0; j < 4; j++) {
        int q = wq * 64 + j * 16 + r15;
        if (q < d.nvalid) {
            unsigned short* orow = simsb + (size_t)(sbase + q) * NMEM + n0;
#pragma unroll
            for (int i = 0; i < 4; i++) {
                int nb = wn * 64 + i * 16 + g * 4;
                float4 iv = *(const float4*)(inv_kn + (size_t)d.a * NMEM + n0 + nb);
                __bf16 e0 = (__bf16)(acc[i][j][0] * iv.x);
                __bf16 e1 = (__bf16)(acc[i][j][1] * iv.y);
                __bf16 e2 = (__bf16)(acc[i][j][2] * iv.z);
                __bf16 e3 = (__bf16)(acc[i][j][3] * iv.w);
                ushort4 o;
                o.x = __builtin_bit_cast(unsigned short, e0);
                o.y = __builtin_bit_cast(unsigned short, e1);
                o.z = __builtin_bit_cast(unsigned short, e2);
                o.w = __builtin_bit_cast(unsigned short, e3);
                *(ushort4*)(orow + nb) = o;
            }
        }
    }
}

// ---------------------------------------------------------------------------
// k_topk v5: binary-search tau + exact recompute + VERBATIM rank select /
// softmax / gather + fused qnorm epilogue writing PING-PONG qn/qb buffers.
__global__ __launch_bounds__(256) void k_topk(
    const unsigned short* __restrict__ simsb,
    const int* __restrict__ sorted_b, const int* __restrict__ sorted_a,
    int chunk_row0,
    const float* __restrict__ qn, const float* __restrict__ keys,
    const float* __restrict__ inv_kn,
    const float* __restrict__ memv, float* __restrict__ cur_next,
    float* __restrict__ qn_out, unsigned short* __restrict__ qb_out) {
    int tid = threadIdx.x;
    int s = chunk_row0 + blockIdx.x;
    int b = sorted_b[s], a = sorted_a[s];
    const unsigned short* row = simsb + (size_t)blockIdx.x * NMEM;

    __shared__ unsigned cnum;
    __shared__ int   cidx[RCAP];
    __shared__ float cval[RCAP];
    __shared__ __align__(16) float qs[DIM];
    __shared__ float selw[TOPK];
    __shared__ int   seli[TOPK];
    __shared__ int   wred[2][4];
    __shared__ float w4[4];

    // cache full bf16 row: 8 uint4 per thread; fmap16 in place (packed).
    uint4 rr[8];
#pragma unroll
    for (int c = 0; c < 8; c++) {
        uint4 v = ((const uint4*)row)[c * 256 + tid];
        unsigned s0 = (v.x >> 15) & 0x00010001u;
        unsigned s1 = (v.y >> 15) & 0x00010001u;
        unsigned s2 = (v.z >> 15) & 0x00010001u;
        unsigned s3 = (v.w >> 15) & 0x00010001u;
        v.x ^= 0x80008000u | (s0 * 0x7FFFu);
        v.y ^= 0x80008000u | (s1 * 0x7FFFu);
        v.z ^= 0x80008000u | (s2 * 0x7FFFu);
        v.w ^= 0x80008000u | (s3 * 0x7FFFu);
        rr[c] = v;
    }

    qs[tid]       = qn[(size_t)b * DIM + tid];
    qs[tid + 256] = qn[(size_t)b * DIM + tid + 256];
    if (tid == 0) cnum = 0;

    // binary search: largest tau with count(key16 >= tau) >= MSEL
    unsigned lo = 0, hi = 65536;
    for (int it = 0; it < 16; ++it) {
        unsigned mid = (lo + hi) >> 1;
        int cnt = 0;
#pragma unroll
        for (int c = 0; c < 8; c++) {
            unsigned w0 = rr[c].x, w1 = rr[c].y, w2 = rr[c].z, w3 = rr[c].w;
            cnt += ((w0 & 0xFFFFu) >= mid) + ((w0 >> 16) >= mid);
            cnt += ((w1 & 0xFFFFu) >= mid) + ((w1 >> 16) >= mid);
            cnt += ((w2 & 0xFFFFu) >= mid) + ((w2 >> 16) >= mid);
            cnt += ((w3 & 0xFFFFu) >= mid) + ((w3 >> 16) >= mid);
        }
        for (int o = 32; o; o >>= 1) cnt += __shfl_down(cnt, o);
        if ((tid & 63) == 0) wred[it & 1][tid >> 6] = cnt;
        __syncthreads();
        int tot = wred[it & 1][0] + wred[it & 1][1] + wred[it & 1][2] + wred[it & 1][3];
        if ((unsigned)tot >= MSEL) lo = mid; else hi = mid;
    }
    unsigned tau16 = lo;

    // collect candidates
#pragma unroll
    for (int c = 0; c < 8; c++) {
        unsigned uu[4] = {rr[c].x, rr[c].y, rr[c].z, rr[c].w};
#pragma unroll
        for (int q2 = 0; q2 < 4; q2++) {
#pragma unroll
            for (int hh = 0; hh < 2; hh++) {
                unsigned u16v = hh ? (uu[q2] >> 16) : (uu[q2] & 0xFFFFu);
                if (u16v >= tau16) {
                    unsigned p = atomicAdd(&cnum, 1u);
                    if (p < RCAP) cidx[p] = (c * 256 + tid) * 8 + q2 * 2 + hh;
                }
            }
        }
    }
    __syncthreads();
    int ncand = (int)cnum; if (ncand > RCAP) ncand = RCAP;

    // exact fp32 recompute: bit-identical chain (fmaf, k ascending; * inv once)
    const float* kbase = keys + (size_t)a * NMEM * DIM;
    const float* invp  = inv_kn + (size_t)a * NMEM;
    for (int i = tid; i < ncand; i += 256) {
        int n = cidx[i];
        const float4* kr = (const float4*)(kbase + (size_t)n * DIM);
        float acc = 0.f;
#pragma unroll 8
        for (int k4 = 0; k4 < DIM / 4; k4++) {
            float4 v = kr[k4];
            float4 qv = *(const float4*)&qs[k4 * 4];
            acc = fmaf(qv.x, v.x, acc);
            acc = fmaf(qv.y, v.y, acc);
            acc = fmaf(qv.z, v.z, acc);
            acc = fmaf(qv.w, v.w, acc);
        }
        cval[i] = acc * invp[n];
    }
    __syncthreads();

    // exact rank select among candidates (f32 desc, index asc) — verbatim
    for (int i = tid; i < ncand; i += 256) {
        float si = cval[i]; int ni = cidx[i];
        int rank = 0;
        for (int j = 0; j < ncand; j++) {
            float sj = cval[j];
            rank += (sj > si) || (sj == si && cidx[j] < ni);
        }
        if (rank < TOPK) { selw[rank] = si; seli[rank] = ni; }
    }
    __syncthreads();
    if (tid == 0) {
        float mx = selw[0];
        for (int i = 1; i < TOPK; i++) mx = fmaxf(mx, selw[i]);
        float ssum = 0.f;
        for (int i = 0; i < TOPK; i++) { float e = expf(selw[i] - mx); selw[i] = e; ssum += e; }
        float inv = 1.0f / ssum;
        for (int i = 0; i < TOPK; i++) selw[i] *= inv;
    }
    __syncthreads();

    const float* mv = memv + (size_t)a * NMEM * DIM;
    float acc0 = 0.f, acc1 = 0.f;
#pragma unroll 10
    for (int i = 0; i < TOPK; i++) {
        const float* vr = mv + (size_t)seli[i] * DIM;
        float wgt = selw[i];
        acc0 += wgt * vr[tid];
        acc1 += wgt * vr[tid + 256];
    }
    float* o = cur_next + (size_t)b * DIM;
    o[tid] = acc0;
    o[tid + 256] = acc1;

    // fused qnorm: replicate k_qnorm's exact reduction on this row's values.
    float ss = 0.f;
    { float v = acc0; ss += v * v; }
    { float v = acc1; ss += v * v; }
    for (int o2 = 32; o2; o2 >>= 1) ss += __shfl_down(ss, o2);
    if ((tid & 63) == 0) w4[tid >> 6] = ss;
    __syncthreads();
    float tot = w4[0] + w4[1] + w4[2] + w4[3];
    float sc = 1.0f / (sqrtf(tot) + 1e-8f);
    float v0 = acc0 * sc, v1 = acc1 * sc;
    qn_out[(size_t)b * DIM + tid]       = v0;
    qn_out[(size_t)b * DIM + tid + 256] = v1;
    __bf16 h0 = (__bf16)v0, h1 = (__bf16)v1;
    qb_out[(size_t)b * DIM + tid]       = __builtin_bit_cast(unsigned short, h0);
    qb_out[(size_t)b * DIM + tid + 256] = __builtin_bit_cast(unsigned short, h1);
}

// ---------------------------------------------------------------------------
// VERBATIM k_mlp.
__global__ __launch_bounds__(256) void k_mlp(
    const float* __restrict__ x,
    const float* __restrict__ W1, const float* __restrict__ b1,
    const float* __restrict__ W2, const float* __restrict__ b2,
    const float* __restrict__ W3, const float* __restrict__ b3,
    float* __restrict__ out, int out_off, int out_stride) {
    int w = threadIdx.x >> 6, lane = threadIdx.x & 63;
    int b = blockIdx.x * 4 + w;
    __shared__ float xs[4][DIM];
    __shared__ float h1s[4][H1N];
    const float* xr = x + (size_t)b * DIM;
#pragma unroll
    for (int i = 0; i < 2; i++) {
        float4 v = *(const float4*)(xr + (lane + i * 64) * 4);
        *(float4*)&xs[w][(lane + i * 64) * 4] = v;
    }
    __syncthreads();
    float a0 = b1[lane], a1 = b1[lane + 64], a2 = b1[lane + 128], a3 = b1[lane + 192];
    for (int k = 0; k < DIM; k++) {
        float xv = xs[w][k];
        const float* wr = W1 + k * H1N;
        a0 += xv * wr[lane];
        a1 += xv * wr[lane + 64];
        a2 += xv * wr[lane + 128];
        a3 += xv * wr[lane + 192];
    }
    h1s[w][lane]       = (a0 > 0.f) ? a0 : expm1f(a0);
    h1s[w][lane + 64]  = (a1 > 0.f) ? a1 : expm1f(a1);
    h1s[w][lane + 128] = (a2 > 0.f) ? a2 : expm1f(a2);
    h1s[w][lane + 192] = (a3 > 0.f) ? a3 : expm1f(a3);
    __syncthreads();
    float c0 = b2[lane], c1 = b2[lane + 64];
    for (int k = 0; k < H1N; k++) {
        float hv = h1s[w][k];
        c0 += hv * W2[k * H2N + lane];
        c1 += hv * W2[k * H2N + lane + 64];
    }
    c0 = ((c0 > 0.f) ? c0 : expm1f(c0)) * W3[lane];
    c1 = ((c1 > 0.f) ? c1 : expm1f(c1)) * W3[lane + 64];
    float ssum = c0 + c1;
    for (int o = 32; o; o >>= 1) ssum += __shfl_down(ssum, o);
    if (lane == 0) out[out_off + b * out_stride] = ssum + b3[0];
}

// ---------------------------------------------------------------------------
extern "C" void kernel_launch(void* const* d_in, const int* in_sizes, int n_in,
                              void* d_out, int out_size, void* d_ws, size_t ws_size,
                              hipStream_t stream) {
    const float* emb  = (const float*)d_in[0];
    const float* keys = (const float*)d_in[1];
    const float* memv = (const float*)d_in[2];
    const float* W1 = (const float*)d_in[3];
    const float* b1 = (const float*)d_in[4];
    const float* W2 = (const float*)d_in[5];
    const float* b2 = (const float*)d_in[6];
    const float* W3 = (const float*)d_in[7];
    const float* b3 = (const float*)d_in[8];
    const int* actions = (const int*)d_in[9];
    float* out = (float*)d_out;

    char* ws = (char*)d_ws;
    size_t off = 0;
    auto alloc = [&](size_t bytes) -> void* {
        void* p = ws + off;
        off = (off + bytes + 255) & ~(size_t)255;
        return p;
    };
    float* inv_kn  = (float*)alloc(sizeof(float) * A_CNT * NMEM);
    float* qnA     = (float*)alloc(sizeof(float) * NB * DIM);
    float* qnB     = (float*)alloc(sizeof(float) * NB * DIM);
    unsigned short* qbA = (unsigned short*)alloc(sizeof(unsigned short) * NB * DIM);
    unsigned short* qbB = (unsigned short*)alloc(sizeof(unsigned short) * NB * DIM);
    unsigned short* kb = (unsigned short*)alloc(sizeof(unsigned short) * (size_t)A_CNT * NMEM * DIM);
    float* curA    = (float*)alloc(sizeof(float) * NB * DIM);
    int* sorted_b  = (int*)alloc(sizeof(int) * NSTEPS * NB);
    int* sorted_a  = (int*)alloc(sizeof(int) * NSTEPS * NB);
    TileDesc* descs = (TileDesc*)alloc(sizeof(TileDesc) * 64 * NSTEPS);
    size_t rem = (ws_size > off) ? (ws_size - off) : 0;
    int CB = 256;
    if (rem >= sizeof(unsigned short) * (size_t)1024 * NMEM + 4096) CB = 1024;
    else if (rem >= sizeof(unsigned short) * (size_t)512 * NMEM + 4096) CB = 512;
    unsigned short* simsb = (unsigned short*)alloc(sizeof(unsigned short) * (size_t)CB * NMEM);
    int nch = NB / CB;
    int maxd = CB / TM + A_CNT;

    k_prep_keys<<<dim3(A_CNT * NMEM / 4), dim3(256), 0, stream>>>(keys, inv_kn, kb);
    k_mlp<<<dim3(NB / 4), dim3(256), 0, stream>>>(emb, W1, b1, W2, b2, W3, b3, out, 0, 1);
    k_group_all<<<dim3(NSTEPS), dim3(64), 0, stream>>>(actions, sorted_b, sorted_a, descs, CB, maxd, nch);
    k_qnorm<<<dim3(NB), dim3(256), 0, stream>>>(emb, qnA, qbA);

    float* nxt = curA;
    float* qn_cur = qnA;  unsigned short* qb_cur = qbA;
    float* qn_nxt = qnB;  unsigned short* qb_nxt = qbB;
    for (int t = 0; t < NSTEPS; t++) {
        const int* sb = sorted_b + t * NB;
        const int* sa = sorted_a + t * NB;
        TileDesc* dsc = descs + t * (nch * maxd);
        for (int c = 0; c < nch; c++) {
            k_screen<<<dim3(maxd, NMEM / TN), dim3(256), 0, stream>>>(
                qb_cur, kb, inv_kn, sb, dsc + c * maxd, c * CB, simsb);
            k_topk<<<dim3(CB), dim3(256), 0, stream>>>(
                simsb, sb, sa, c * CB, qn_cur, keys, inv_kn, memv, nxt, qn_nxt, qb_nxt);
        }
        k_mlp<<<dim3(NB / 4), dim3(256), 0, stream>>>(nxt, W1, b1, W2, b2, W3, b3, out, NB + t, NSTEPS);
        { float* tf = qn_cur; qn_cur = qn_nxt; qn_nxt = tf; }
        { unsigned short* ts = qb_cur; qb_cur = qb_nxt; qb_nxt = ts; }
    }
}

// Round 6
// 1056.684 us; speedup vs baseline: 2.2239x; 1.2147x over previous
//
#include <hip/hip_runtime.h>

#define A_CNT   5
#define NB      1024
#define DIM     512
#define NMEM    16384
#define TOPK    50
#define NSTEPS  5
#define H1N     256
#define H2N     128

#define TM      128
#define TN      128
#define MSEL    100     // screen candidates per row (slack over TOPK=50)
#define RCAP    512     // candidate buffer cap

struct TileDesc { int a; int s0; int nvalid; int pad; };

typedef __bf16 bf16x8 __attribute__((ext_vector_type(8)));
typedef short  s16x8  __attribute__((ext_vector_type(8)));
typedef float  f32x4  __attribute__((ext_vector_type(4)));

// SFINAE hedge for the bf16 MFMA builtin operand type across toolchains.
template <typename T>
__device__ __forceinline__ auto mfma_try(T a, T b, f32x4 c, int)
    -> decltype(__builtin_amdgcn_mfma_f32_16x16x32_bf16(a, b, c, 0, 0, 0)) {
    return __builtin_amdgcn_mfma_f32_16x16x32_bf16(a, b, c, 0, 0, 0);
}
template <typename T>
__device__ __forceinline__ f32x4 mfma_try(T a, T b, f32x4 c, long) {
    return __builtin_amdgcn_mfma_f32_16x16x32_bf16(
        __builtin_bit_cast(s16x8, a), __builtin_bit_cast(s16x8, b), c, 0, 0, 0);
}
__device__ __forceinline__ f32x4 mfma_bf16(uint4 a, uint4 b, f32x4 c) {
    return mfma_try(__builtin_bit_cast(bf16x8, a), __builtin_bit_cast(bf16x8, b), c, 0);
}

union BF8 { bf16x8 v; uint4 u; };

// async global->LDS, 16B per lane (dest = wave-uniform base + lane*16).
__device__ __forceinline__ void gload_lds16(const void* g, void* l) {
    __builtin_amdgcn_global_load_lds(
        (const __attribute__((address_space(1))) void*)(unsigned long long)g,
        (__attribute__((address_space(3))) void*)(unsigned)(unsigned long long)l,
        16, 0, 0);
}

// ---------------------------------------------------------------------------
// k_prep_keys: fused inv-norm (VERBATIM reduction chain) + one-time fp32->bf16
// key conversion.
__global__ __launch_bounds__(256) void k_prep_keys(const float* __restrict__ keys,
                                                   float* __restrict__ inv,
                                                   unsigned short* __restrict__ kb) {
    int row  = blockIdx.x * 4 + (threadIdx.x >> 6);
    int lane = threadIdx.x & 63;
    const float* p = keys + (size_t)row * DIM;
    float ss = 0.f;
    for (int i = lane; i < DIM; i += 64) { float v = p[i]; ss += v * v; }
    for (int o = 32; o; o >>= 1) ss += __shfl_down(ss, o);
    ss = __shfl(ss, 0);
    if (lane == 0) inv[row] = 1.0f / (sqrtf(ss) + 1e-8f);
    const float4* s4 = (const float4*)(p + lane * 8);
    float4 v0 = s4[0], v1 = s4[1];
    BF8 pk;
    pk.v[0] = (__bf16)v0.x; pk.v[1] = (__bf16)v0.y;
    pk.v[2] = (__bf16)v0.z; pk.v[3] = (__bf16)v0.w;
    pk.v[4] = (__bf16)v1.x; pk.v[5] = (__bf16)v1.y;
    pk.v[6] = (__bf16)v1.z; pk.v[7] = (__bf16)v1.w;
    *(uint4*)(kb + (size_t)row * DIM + lane * 8) = pk.u;
}

// k_qnorm (step-0 only): VERBATIM fp32 path + bf16 mirror.
__global__ __launch_bounds__(256) void k_qnorm(const float* __restrict__ x,
                                               float* __restrict__ qn,
                                               unsigned short* __restrict__ qb) {
    int row = blockIdx.x, tid = threadIdx.x;
    const float* p = x + (size_t)row * DIM;
    float ss = 0.f;
    for (int i = tid; i < DIM; i += 256) { float v = p[i]; ss += v * v; }
    for (int o = 32; o; o >>= 1) ss += __shfl_down(ss, o);
    __shared__ float w4[4];
    if ((tid & 63) == 0) w4[tid >> 6] = ss;
    __syncthreads();
    float tot = w4[0] + w4[1] + w4[2] + w4[3];
    float s = 1.0f / (sqrtf(tot) + 1e-8f);
    float* q = qn + (size_t)row * DIM;
    unsigned short* qbr = qb + (size_t)row * DIM;
    for (int i = tid; i < DIM; i += 256) {
        float v = p[i] * s;
        q[i] = v;
        __bf16 h = (__bf16)v;
        qbr[i] = __builtin_bit_cast(unsigned short, h);
    }
}

// k_group_all: all NSTEPS groupings upfront (depends only on actions).
__global__ void k_group_all(const int* __restrict__ actions,
                            int* __restrict__ sorted_b_all, int* __restrict__ sorted_a_all,
                            TileDesc* __restrict__ descs_all, int cb, int maxd, int nch) {
    int t = blockIdx.x;
    int* sorted_b = sorted_b_all + t * NB;
    int* sorted_a = sorted_a_all + t * NB;
    TileDesc* descs = descs_all + t * (nch * maxd);
    int lane = threadIdx.x;  // blockDim = 64
    for (int i = lane; i < nch * maxd; i += 64) descs[i].a = -1;
    __shared__ int gs[A_CNT + 1];
    int out_pos = 0;
    for (int a = 0; a < A_CNT; a++) {
        if (lane == 0) gs[a] = out_pos;
        for (int c = 0; c < NB; c += 64) {
            int b = c + lane;
            int act = actions[b * NSTEPS + t];
            unsigned long long m = __ballot(act == a);
            int rank = __popcll(m & ((1ULL << lane) - 1ULL));
            if (act == a) { sorted_b[out_pos + rank] = b; sorted_a[out_pos + rank] = a; }
            out_pos += __popcll(m);
        }
    }
    if (lane == 0) {
        gs[A_CNT] = NB;
        int ndc[4] = {0, 0, 0, 0};
        for (int a = 0; a < A_CNT; a++) {
            int s = gs[a], e = gs[a + 1];
            while (s < e) {
                int c = s / cb;
                int lim = min(e, (c + 1) * cb);
                int len = min(TM, lim - s);
                TileDesc d; d.a = a; d.s0 = s; d.nvalid = len; d.pad = 0;
                descs[c * maxd + ndc[c]++] = d;
                s += len;
            }
        }
    }
}

// ---------------------------------------------------------------------------
// k_screen: ROUND-5 VERBATIM (passing, bit-verified).
__global__ __launch_bounds__(256) void k_screen(
    const unsigned short* __restrict__ qb, const unsigned short* __restrict__ kb,
    const float* __restrict__ inv_kn, const int* __restrict__ sorted_b,
    const TileDesc* __restrict__ descs, int chunk_row0,
    unsigned short* __restrict__ simsb) {
    TileDesc d = descs[blockIdx.x];
    if (d.a < 0) return;
    int tid = threadIdx.x;
    int n0 = blockIdx.y * TN;
    __shared__ __align__(16) unsigned short Qs[TM][32];
    __shared__ __align__(16) unsigned short Ks[TN][32];
    __shared__ int rows[TM];
    if (tid < TM) rows[tid] = sorted_b[d.s0 + min(tid, d.nvalid - 1)];
    __syncthreads();

    int w = tid >> 6, lane = tid & 63;
    int g = lane >> 4, r15 = lane & 15;
    int wq = w >> 1, wn = w & 1;
    int swc = (g ^ ((r15 >> 1) & 3)) * 8;   // swizzled frag column (u16 units)

    int srow = tid >> 2, schunk = ((tid & 3) ^ ((tid >> 3) & 3)) * 8;
    const unsigned short* kbase = kb + (size_t)d.a * NMEM * DIM;
    const unsigned short* q0 = qb + (size_t)rows[srow] * DIM + schunk;
    const unsigned short* q1 = qb + (size_t)rows[64 + srow] * DIM + schunk;
    const unsigned short* k0p = kbase + (size_t)(n0 + srow) * DIM + schunk;
    const unsigned short* k1p = kbase + (size_t)(n0 + 64 + srow) * DIM + schunk;
    char* ldsQ = (char*)&Qs[0][0] + tid * 16;
    char* ldsK = (char*)&Ks[0][0] + tid * 16;

    f32x4 acc[4][4];
#pragma unroll
    for (int i = 0; i < 4; i++)
#pragma unroll
        for (int j = 0; j < 4; j++) acc[i][j] = (f32x4){0.f, 0.f, 0.f, 0.f};

    for (int k0 = 0; k0 < DIM; k0 += 32) {
        gload_lds16(q0 + k0,  ldsQ);
        gload_lds16(q1 + k0,  ldsQ + 4096);
        gload_lds16(k0p + k0, ldsK);
        gload_lds16(k1p + k0, ldsK + 4096);
        __syncthreads();
        uint4 kf[4], qf[4];
#pragma unroll
        for (int m = 0; m < 4; m++)
            kf[m] = *(const uint4*)&Ks[wn * 64 + m * 16 + r15][swc];
#pragma unroll
        for (int m = 0; m < 4; m++)
            qf[m] = *(const uint4*)&Qs[wq * 64 + m * 16 + r15][swc];
#pragma unroll
        for (int i = 0; i < 4; i++)
#pragma unroll
            for (int j = 0; j < 4; j++)
                acc[i][j] = mfma_bf16(kf[i], qf[j], acc[i][j]);
        __syncthreads();
    }

    int sbase = d.s0 - chunk_row0;
#pragma unroll
    for (int j = 0; j < 4; j++) {
        int q = wq * 64 + j * 16 + r15;
        if (q < d.nvalid) {
            unsigned short* orow = simsb + (size_t)(sbase + q) * NMEM + n0;
#pragma unroll
            for (int i = 0; i < 4; i++) {
                int nb = wn * 64 + i * 16 + g * 4;
                float4 iv = *(const float4*)(inv_kn + (size_t)d.a * NMEM + n0 + nb);
                __bf16 e0 = (__bf16)(acc[i][j][0] * iv.x);
                __bf16 e1 = (__bf16)(acc[i][j][1] * iv.y);
                __bf16 e2 = (__bf16)(acc[i][j][2] * iv.z);
                __bf16 e3 = (__bf16)(acc[i][j][3] * iv.w);
                ushort4 o;
                o.x = __builtin_bit_cast(unsigned short, e0);
                o.y = __builtin_bit_cast(unsigned short, e1);
                o.z = __builtin_bit_cast(unsigned short, e2);
                o.w = __builtin_bit_cast(unsigned short, e3);
                *(ushort4*)(orow + nb) = o;
            }
        }
    }
}

// ---------------------------------------------------------------------------
// k_topk: ROUND-5 VERBATIM body (passing, bit-verified); cur_next now points
// into the per-step slot of curAll (pointer arithmetic only).
__global__ __launch_bounds__(256) void k_topk(
    const unsigned short* __restrict__ simsb,
    const int* __restrict__ sorted_b, const int* __restrict__ sorted_a,
    int chunk_row0,
    const float* __restrict__ qn, const float* __restrict__ keys,
    const float* __restrict__ inv_kn,
    const float* __restrict__ memv, float* __restrict__ cur_next,
    float* __restrict__ qn_out, unsigned short* __restrict__ qb_out) {
    int tid = threadIdx.x;
    int s = chunk_row0 + blockIdx.x;
    int b = sorted_b[s], a = sorted_a[s];
    const unsigned short* row = simsb + (size_t)blockIdx.x * NMEM;

    __shared__ unsigned cnum;
    __shared__ int   cidx[RCAP];
    __shared__ float cval[RCAP];
    __shared__ __align__(16) float qs[DIM];
    __shared__ float selw[TOPK];
    __shared__ int   seli[TOPK];
    __shared__ int   wred[2][4];
    __shared__ float w4[4];

    uint4 rr[8];
#pragma unroll
    for (int c = 0; c < 8; c++) {
        uint4 v = ((const uint4*)row)[c * 256 + tid];
        unsigned s0 = (v.x >> 15) & 0x00010001u;
        unsigned s1 = (v.y >> 15) & 0x00010001u;
        unsigned s2 = (v.z >> 15) & 0x00010001u;
        unsigned s3 = (v.w >> 15) & 0x00010001u;
        v.x ^= 0x80008000u | (s0 * 0x7FFFu);
        v.y ^= 0x80008000u | (s1 * 0x7FFFu);
        v.z ^= 0x80008000u | (s2 * 0x7FFFu);
        v.w ^= 0x80008000u | (s3 * 0x7FFFu);
        rr[c] = v;
    }

    qs[tid]       = qn[(size_t)b * DIM + tid];
    qs[tid + 256] = qn[(size_t)b * DIM + tid + 256];
    if (tid == 0) cnum = 0;

    unsigned lo = 0, hi = 65536;
    for (int it = 0; it < 16; ++it) {
        unsigned mid = (lo + hi) >> 1;
        int cnt = 0;
#pragma unroll
        for (int c = 0; c < 8; c++) {
            unsigned w0 = rr[c].x, w1 = rr[c].y, w2 = rr[c].z, w3 = rr[c].w;
            cnt += ((w0 & 0xFFFFu) >= mid) + ((w0 >> 16) >= mid);
            cnt += ((w1 & 0xFFFFu) >= mid) + ((w1 >> 16) >= mid);
            cnt += ((w2 & 0xFFFFu) >= mid) + ((w2 >> 16) >= mid);
            cnt += ((w3 & 0xFFFFu) >= mid) + ((w3 >> 16) >= mid);
        }
        for (int o = 32; o; o >>= 1) cnt += __shfl_down(cnt, o);
        if ((tid & 63) == 0) wred[it & 1][tid >> 6] = cnt;
        __syncthreads();
        int tot = wred[it & 1][0] + wred[it & 1][1] + wred[it & 1][2] + wred[it & 1][3];
        if ((unsigned)tot >= MSEL) lo = mid; else hi = mid;
    }
    unsigned tau16 = lo;

#pragma unroll
    for (int c = 0; c < 8; c++) {
        unsigned uu[4] = {rr[c].x, rr[c].y, rr[c].z, rr[c].w};
#pragma unroll
        for (int q2 = 0; q2 < 4; q2++) {
#pragma unroll
            for (int hh = 0; hh < 2; hh++) {
                unsigned u16v = hh ? (uu[q2] >> 16) : (uu[q2] & 0xFFFFu);
                if (u16v >= tau16) {
                    unsigned p = atomicAdd(&cnum, 1u);
                    if (p < RCAP) cidx[p] = (c * 256 + tid) * 8 + q2 * 2 + hh;
                }
            }
        }
    }
    __syncthreads();
    int ncand = (int)cnum; if (ncand > RCAP) ncand = RCAP;

    const float* kbase = keys + (size_t)a * NMEM * DIM;
    const float* invp  = inv_kn + (size_t)a * NMEM;
    for (int i = tid; i < ncand; i += 256) {
        int n = cidx[i];
        const float4* kr = (const float4*)(kbase + (size_t)n * DIM);
        float acc = 0.f;
#pragma unroll 8
        for (int k4 = 0; k4 < DIM / 4; k4++) {
            float4 v = kr[k4];
            float4 qv = *(const float4*)&qs[k4 * 4];
            acc = fmaf(qv.x, v.x, acc);
            acc = fmaf(qv.y, v.y, acc);
            acc = fmaf(qv.z, v.z, acc);
            acc = fmaf(qv.w, v.w, acc);
        }
        cval[i] = acc * invp[n];
    }
    __syncthreads();

    for (int i = tid; i < ncand; i += 256) {
        float si = cval[i]; int ni = cidx[i];
        int rank = 0;
        for (int j = 0; j < ncand; j++) {
            float sj = cval[j];
            rank += (sj > si) || (sj == si && cidx[j] < ni);
        }
        if (rank < TOPK) { selw[rank] = si; seli[rank] = ni; }
    }
    __syncthreads();
    if (tid == 0) {
        float mx = selw[0];
        for (int i = 1; i < TOPK; i++) mx = fmaxf(mx, selw[i]);
        float ssum = 0.f;
        for (int i = 0; i < TOPK; i++) { float e = expf(selw[i] - mx); selw[i] = e; ssum += e; }
        float inv = 1.0f / ssum;
        for (int i = 0; i < TOPK; i++) selw[i] *= inv;
    }
    __syncthreads();

    const float* mv = memv + (size_t)a * NMEM * DIM;
    float acc0 = 0.f, acc1 = 0.f;
#pragma unroll 10
    for (int i = 0; i < TOPK; i++) {
        const float* vr = mv + (size_t)seli[i] * DIM;
        float wgt = selw[i];
        acc0 += wgt * vr[tid];
        acc1 += wgt * vr[tid + 256];
    }
    float* o = cur_next + (size_t)b * DIM;
    o[tid] = acc0;
    o[tid + 256] = acc1;

    // fused qnorm: replicate k_qnorm's exact reduction on this row's values.
    float ss = 0.f;
    { float v = acc0; ss += v * v; }
    { float v = acc1; ss += v * v; }
    for (int o2 = 32; o2; o2 >>= 1) ss += __shfl_down(ss, o2);
    if ((tid & 63) == 0) w4[tid >> 6] = ss;
    __syncthreads();
    float tot = w4[0] + w4[1] + w4[2] + w4[3];
    float sc = 1.0f / (sqrtf(tot) + 1e-8f);
    float v0 = acc0 * sc, v1 = acc1 * sc;
    qn_out[(size_t)b * DIM + tid]       = v0;
    qn_out[(size_t)b * DIM + tid + 256] = v1;
    __bf16 h0 = (__bf16)v0, h1 = (__bf16)v1;
    qb_out[(size_t)b * DIM + tid]       = __builtin_bit_cast(unsigned short, h0);
    qb_out[(size_t)b * DIM + tid + 256] = __builtin_bit_cast(unsigned short, h1);
}

// ---------------------------------------------------------------------------
// k_mlp_all: ONE batched launch over all 6144 rows (emb -> pred_values, then
// 5 step outputs -> pred_nstep). Per-row arithmetic is the VERBATIM k_mlp
// body (same FMA order, same ELU, same reduce) — only x pointer and output
// index mapping differ -> bit-identical outputs. 1536 blocks (~192 CUs) vs
// six serial 256-block launches (~32 CUs each).
__global__ __launch_bounds__(256) void k_mlp_all(
    const float* __restrict__ emb, const float* __restrict__ steps,
    const float* __restrict__ W1, const float* __restrict__ b1,
    const float* __restrict__ W2, const float* __restrict__ b2,
    const float* __restrict__ W3, const float* __restrict__ b3,
    float* __restrict__ out) {
    int w = threadIdx.x >> 6, lane = threadIdx.x & 63;
    int r = blockIdx.x * 4 + w;          // 0 .. 6*NB-1
    const float* xr;
    int oidx;
    if (r < NB) {
        xr = emb + (size_t)r * DIM;
        oidx = r;                         // pred_values: out[b]
    } else {
        int rr = r - NB;                  // rr = t*NB + b
        int t = rr / NB, b = rr - t * NB;
        xr = steps + (size_t)rr * DIM;
        oidx = NB + b * NSTEPS + t;       // pred_nstep: out[NB + b*5 + t]
    }
    __shared__ float xs[4][DIM];
    __shared__ float h1s[4][H1N];
#pragma unroll
    for (int i = 0; i < 2; i++) {
        float4 v = *(const float4*)(xr + (lane + i * 64) * 4);
        *(float4*)&xs[w][(lane + i * 64) * 4] = v;
    }
    __syncthreads();
    float a0 = b1[lane], a1 = b1[lane + 64], a2 = b1[lane + 128], a3 = b1[lane + 192];
    for (int k = 0; k < DIM; k++) {
        float xv = xs[w][k];
        const float* wr = W1 + k * H1N;
        a0 += xv * wr[lane];
        a1 += xv * wr[lane + 64];
        a2 += xv * wr[lane + 128];
        a3 += xv * wr[lane + 192];
    }
    h1s[w][lane]       = (a0 > 0.f) ? a0 : expm1f(a0);
    h1s[w][lane + 64]  = (a1 > 0.f) ? a1 : expm1f(a1);
    h1s[w][lane + 128] = (a2 > 0.f) ? a2 : expm1f(a2);
    h1s[w][lane + 192] = (a3 > 0.f) ? a3 : expm1f(a3);
    __syncthreads();
    float c0 = b2[lane], c1 = b2[lane + 64];
    for (int k = 0; k < H1N; k++) {
        float hv = h1s[w][k];
        c0 += hv * W2[k * H2N + lane];
        c1 += hv * W2[k * H2N + lane + 64];
    }
    c0 = ((c0 > 0.f) ? c0 : expm1f(c0)) * W3[lane];
    c1 = ((c1 > 0.f) ? c1 : expm1f(c1)) * W3[lane + 64];
    float ssum = c0 + c1;
    for (int o = 32; o; o >>= 1) ssum += __shfl_down(ssum, o);
    if (lane == 0) out[oidx] = ssum + b3[0];
}

// ---------------------------------------------------------------------------
extern "C" void kernel_launch(void* const* d_in, const int* in_sizes, int n_in,
                              void* d_out, int out_size, void* d_ws, size_t ws_size,
                              hipStream_t stream) {
    const float* emb  = (const float*)d_in[0];
    const float* keys = (const float*)d_in[1];
    const float* memv = (const float*)d_in[2];
    const float* W1 = (const float*)d_in[3];
    const float* b1 = (const float*)d_in[4];
    const float* W2 = (const float*)d_in[5];
    const float* b2 = (const float*)d_in[6];
    const float* W3 = (const float*)d_in[7];
    const float* b3 = (const float*)d_in[8];
    const int* actions = (const int*)d_in[9];
    float* out = (float*)d_out;

    char* ws = (char*)d_ws;
    size_t off = 0;
    auto alloc = [&](size_t bytes) -> void* {
        void* p = ws + off;
        off = (off + bytes + 255) & ~(size_t)255;
        return p;
    };
    float* inv_kn  = (float*)alloc(sizeof(float) * A_CNT * NMEM);
    float* qnA     = (float*)alloc(sizeof(float) * NB * DIM);
    float* qnB     = (float*)alloc(sizeof(float) * NB * DIM);
    unsigned short* qbA = (unsigned short*)alloc(sizeof(unsigned short) * NB * DIM);
    unsigned short* qbB = (unsigned short*)alloc(sizeof(unsigned short) * NB * DIM);
    unsigned short* kb = (unsigned short*)alloc(sizeof(unsigned short) * (size_t)A_CNT * NMEM * DIM);
    float* curAll  = (float*)alloc(sizeof(float) * (size_t)NSTEPS * NB * DIM);
    int* sorted_b  = (int*)alloc(sizeof(int) * NSTEPS * NB);
    int* sorted_a  = (int*)alloc(sizeof(int) * NSTEPS * NB);
    TileDesc* descs = (TileDesc*)alloc(sizeof(TileDesc) * 64 * NSTEPS);
    size_t rem = (ws_size > off) ? (ws_size - off) : 0;
    int CB = 256;
    if (rem >= sizeof(unsigned short) * (size_t)1024 * NMEM + 4096) CB = 1024;
    else if (rem >= sizeof(unsigned short) * (size_t)512 * NMEM + 4096) CB = 512;
    unsigned short* simsb = (unsigned short*)alloc(sizeof(unsigned short) * (size_t)CB * NMEM);
    int nch = NB / CB;
    int maxd = CB / TM + A_CNT;

    k_prep_keys<<<dim3(A_CNT * NMEM / 4), dim3(256), 0, stream>>>(keys, inv_kn, kb);
    k_group_all<<<dim3(NSTEPS), dim3(64), 0, stream>>>(actions, sorted_b, sorted_a, descs, CB, maxd, nch);
    k_qnorm<<<dim3(NB), dim3(256), 0, stream>>>(emb, qnA, qbA);

    float* qn_cur = qnA;  unsigned short* qb_cur = qbA;
    float* qn_nxt = qnB;  unsigned short* qb_nxt = qbB;
    for (int t = 0; t < NSTEPS; t++) {
        const int* sb = sorted_b + t * NB;
        const int* sa = sorted_a + t * NB;
        TileDesc* dsc = descs + t * (nch * maxd);
        float* nxt = curAll + (size_t)t * NB * DIM;
        for (int c = 0; c < nch; c++) {
            k_screen<<<dim3(maxd, NMEM / TN), dim3(256), 0, stream>>>(
                qb_cur, kb, inv_kn, sb, dsc + c * maxd, c * CB, simsb);
            k_topk<<<dim3(CB), dim3(256), 0, stream>>>(
                simsb, sb, sa, c * CB, qn_cur, keys, inv_kn, memv, nxt, qn_nxt, qb_nxt);
        }
        { float* tf = qn_cur; qn_cur = qn_nxt; qn_nxt = tf; }
        { unsigned short* ts = qb_cur; qb_cur = qb_nxt; qb_nxt = ts; }
    }
    // all MLP rows in one launch (emb -> pred_values, 5 step outputs -> pred_nstep)
    k_mlp_all<<<dim3(6 * NB / 4), dim3(256), 0, stream>>>(
        emb, curAll, W1, b1, W2, b2, W3, b3, out);
}